// Round 11
// baseline (289.946 us; speedup 1.0000x reference)
//
#include <hip/hip_runtime.h>

typedef unsigned short ushort_t;
typedef unsigned char uchar_t;
typedef unsigned int uint_t;
typedef __attribute__((ext_vector_type(8))) short bf16x8;
typedef __attribute__((ext_vector_type(4))) float f32x4;

constexpr int L_   = 3;
constexpr int B_   = 8192;
constexpr int H_   = 1024;
constexpr int DOUT_= 80;
constexpr int NACT_= 4096;
constexpr int G3_  = 3 * H_;

static __device__ __forceinline__ ushort_t f2bf(float f) {
    uint_t u = __float_as_uint(f);
    uint_t r = (u + 0x7FFFu + ((u >> 16) & 1u)) >> 16;
    return (ushort_t)r;
}

static __device__ __forceinline__ void gll16(const void* g, void* l) {
    __builtin_amdgcn_global_load_lds(
        (const __attribute__((address_space(1))) uint32_t*)g,
        (__attribute__((address_space(3))) uint32_t*)l, 16, 0, 0);
}

// ---------------- fused prep: mask + weight convert + gather/convert ----------------
__global__ void prep_all(const float* __restrict__ encoded, const float* __restrict__ hidden,
                         const int* __restrict__ idx,
                         const float* __restrict__ wih, const float* __restrict__ whh,
                         const float* __restrict__ wout,
                         ushort_t* __restrict__ oih, ushort_t* __restrict__ ohh,
                         ushort_t* __restrict__ oout,
                         ushort_t* __restrict__ x0, ushort_t* __restrict__ hb,
                         uchar_t* __restrict__ mask) {
    int tid = blockIdx.x * blockDim.x + threadIdx.x;
    int nth = gridDim.x * blockDim.x;
    if (tid < NACT_) mask[idx[tid]] = 1;
    const int NW = L_ * G3_ * H_ / 4;
    for (int i = tid; i < NW; i += nth) {
        float4 a = ((const float4*)wih)[i];
        ushort4 o; o.x = f2bf(a.x); o.y = f2bf(a.y); o.z = f2bf(a.z); o.w = f2bf(a.w);
        ((ushort4*)oih)[i] = o;
        float4 b = ((const float4*)whh)[i];
        ushort4 p; p.x = f2bf(b.x); p.y = f2bf(b.y); p.z = f2bf(b.z); p.w = f2bf(b.w);
        ((ushort4*)ohh)[i] = p;
    }
    const int NO = DOUT_ * H_ / 4;
    for (int i = tid; i < NO; i += nth) {
        float4 a = ((const float4*)wout)[i];
        ushort4 o; o.x = f2bf(a.x); o.y = f2bf(a.y); o.z = f2bf(a.z); o.w = f2bf(a.w);
        ((ushort4*)oout)[i] = o;
    }
    const int C4 = H_ / 4;
    const int PER = NACT_ * C4;
    for (int i = tid; i < 4 * PER; i += nth) {
        int seg = i / PER;
        int rem = i - seg * PER;
        int r = rem / C4, c = rem % C4;
        int gr = idx[r];
        const float* src = (seg == 0) ? (encoded + (size_t)gr * H_)
                                      : (hidden + ((size_t)(seg - 1) * B_ + gr) * H_);
        float4 v = ((const float4*)src)[c];
        ushort4 o; o.x = f2bf(v.x); o.y = f2bf(v.y); o.z = f2bf(v.z); o.w = f2bf(v.w);
        ushort_t* dst = (seg == 0) ? x0 : (hb + (size_t)(seg - 1) * NACT_ * H_);
        ((ushort4*)(dst + (size_t)r * H_))[c] = o;
    }
}

// ---------------- fused GRU layer: m97-structure, 128x96 tile, grid 1024 (4 blocks/CU) ----------------
// Same 2-barrier K-loop, same XOR swizzle (0 conflicts), 3-gate W panel now 96 rows (32 cols).
// 4 waves (2M x 2N); per-wave density identical to the round-10 winner; 2x block residency.
__global__ __launch_bounds__(256, 4) void gru_layer(
    const ushort_t* __restrict__ xb,    // [N,H] bf16 layer input
    const ushort_t* __restrict__ hb,    // [N,H] bf16 gathered hidden
    const float* __restrict__ hid_full, // [B,H] fp32 hidden[i]
    const ushort_t* __restrict__ wih,   // [3H,H] bf16
    const ushort_t* __restrict__ whh,   // [3H,H] bf16
    const float* __restrict__ bih, const float* __restrict__ bhh,
    const int* __restrict__ idx,
    float* __restrict__ out_hid,        // [B,H] fp32
    ushort_t* __restrict__ xnext)       // [N,H] bf16
{
    __shared__ ushort_t As[128 * 64];   // 16 KB
    __shared__ ushort_t Ws[96 * 64];    // 12 KB (3 gates x 32 cols)

    const int tid = threadIdx.x;
    const int bid = blockIdx.x;
    const int swz = (bid & 7) * 128 + (bid >> 3); // XCD-chunked, bijective (1024 % 8 == 0)
    const int bn = swz & 31, bm = swz >> 5;       // 32 col-tiles x 32 row-tiles
    const int row0 = bm * 128, col0 = bn * 32;
    const int wave = tid >> 6, lane = tid & 63;
    const int wr = wave >> 1, wc = wave & 1;      // 2M x 2N wave grid
    const int fl = lane & 15, fh = lane >> 4;
    const int srow = lane >> 3;                   // DMA: row-within-8 for this lane
    const int sxor = ((lane & 7) ^ srow) * 8;     // inverse-swizzled source 16B slot

    f32x4 accR[4] = {};
    f32x4 accZ[4] = {};
    f32x4 accN[2][4] = {};

#pragma unroll
    for (int ph = 0; ph < 2; ++ph) {
        const ushort_t* Asrc = ph ? hb : xb;
        const ushort_t* Wsrc = ph ? whh : wih;
        const ushort_t* abase[4];
        const ushort_t* wbase[3];
#pragma unroll
        for (int t = 0; t < 4; ++t)
            abase[t] = Asrc + (size_t)(row0 + wave * 32 + t * 8 + srow) * H_ + sxor;
#pragma unroll
        for (int t = 0; t < 3; ++t) {
            const int slot = wave * 24 + t * 8 + srow;   // flat W row 0..95 = gate*32 + col
            const int gate = slot >> 5, rowW = slot & 31;
            wbase[t] = Wsrc + (size_t)(gate * H_ + col0 + rowW) * H_ + sxor;
        }
        for (int kk = 0; kk < H_; kk += 64) {
            __syncthreads();
#pragma unroll
            for (int t = 0; t < 4; ++t)
                gll16(abase[t] + kk, &As[(wave * 32 + t * 8) * 64]);
#pragma unroll
            for (int t = 0; t < 3; ++t)
                gll16(wbase[t] + kk, &Ws[(wave * 24 + t * 8) * 64]);
            __syncthreads();
#pragma unroll
            for (int ks = 0; ks < 2; ++ks) {
                const int sl = ((ks * 4 + fh) ^ (fl & 7)) * 8;  // swizzled ds_read slot
                bf16x8 a[4];
#pragma unroll
                for (int m = 0; m < 4; ++m)
                    a[m] = *(const bf16x8*)&As[(wr * 64 + m * 16 + fl) * 64 + sl];
#pragma unroll
                for (int g = 0; g < 3; ++g) {
                    const bf16x8 b = *(const bf16x8*)&Ws[(g * 32 + wc * 16 + fl) * 64 + sl];
#pragma unroll
                    for (int m = 0; m < 4; ++m) {
                        if (g == 0)
                            accR[m] = __builtin_amdgcn_mfma_f32_16x16x32_bf16(a[m], b, accR[m], 0, 0, 0);
                        else if (g == 1)
                            accZ[m] = __builtin_amdgcn_mfma_f32_16x16x32_bf16(a[m], b, accZ[m], 0, 0, 0);
                        else
                            accN[ph][m] = __builtin_amdgcn_mfma_f32_16x16x32_bf16(a[m], b, accN[ph][m], 0, 0, 0);
                    }
                }
            }
        }
    }

    // epilogue: gate math, scatter into out_hid, write bf16 x for next layer
    {
        const int c = col0 + wc * 16 + fl;
        const float br_r = bih[c] + bhh[c];
        const float br_z = bih[H_ + c] + bhh[H_ + c];
        const float bi_n = bih[2 * H_ + c];
        const float bh_n = bhh[2 * H_ + c];
#pragma unroll
        for (int m = 0; m < 4; ++m) {
#pragma unroll
            for (int j = 0; j < 4; ++j) {
                const int r = row0 + wr * 64 + m * 16 + fh * 4 + j;
                const float vr = 1.f / (1.f + expf(-(accR[m][j] + br_r)));
                const float vz = 1.f / (1.f + expf(-(accZ[m][j] + br_z)));
                const float vn = tanhf(accN[0][m][j] + bi_n + vr * (accN[1][m][j] + bh_n));
                const int gr = idx[r];
                const float h0 = hid_full[(size_t)gr * H_ + c];
                const float ho = (1.f - vz) * vn + vz * h0;
                out_hid[(size_t)gr * H_ + c] = ho;
                xnext[(size_t)r * H_ + c] = f2bf(ho);
            }
        }
    }
}

// ---------------- tail: head GEMM (blocks 0..63) + inactive-row copy (blocks 64+) ----------------
__global__ __launch_bounds__(256) void tail_kernel(
    const ushort_t* __restrict__ xb, const ushort_t* __restrict__ wo,
    const float* __restrict__ bo, const int* __restrict__ idx,
    float* __restrict__ outy,
    const float* __restrict__ hidden, const uchar_t* __restrict__ mask,
    float* __restrict__ outh)
{
    __shared__ ushort_t Xs[64][72];
    __shared__ ushort_t Ws[80][72];
    const int tid = threadIdx.x;
    if (blockIdx.x >= 64) {
        // copy part: inactive rows of all 3 layers (disjoint from gru scatter rows)
        const int total = L_ * B_ * (H_ / 4);
        int i = (blockIdx.x - 64) * 256 + tid;
        const int nth = (gridDim.x - 64) * 256;
        for (; i < total; i += nth) {
            int row = (i >> 8) & (B_ - 1);      // 256 float4 per row
            if (mask[row]) continue;
            ((float4*)outh)[i] = ((const float4*)hidden)[i];
        }
        return;
    }
    const int row0 = blockIdx.x * 64;
    const int lrow = tid >> 2, lseg = tid & 3;
    const int wave = tid >> 6, lane = tid & 63;
    const int fl = lane & 15, fh = lane >> 4;
    f32x4 acc[5] = {};

    for (int kk = 0; kk < H_; kk += 64) {
        __syncthreads();
        const ushort_t* xp = xb + (size_t)(row0 + lrow) * H_ + kk + lseg * 16;
        *(uint4*)&Xs[lrow][lseg * 16]     = *(const uint4*)xp;
        *(uint4*)&Xs[lrow][lseg * 16 + 8] = *(const uint4*)(xp + 8);
        for (int t = tid; t < 320; t += 256) {
            int r = t >> 2, s = t & 3;
            const ushort_t* wp = wo + (size_t)r * H_ + kk + s * 16;
            *(uint4*)&Ws[r][s * 16]     = *(const uint4*)wp;
            *(uint4*)&Ws[r][s * 16 + 8] = *(const uint4*)(wp + 8);
        }
        __syncthreads();
#pragma unroll
        for (int ks = 0; ks < 64; ks += 32) {
            bf16x8 a = *(const bf16x8*)&Xs[wave * 16 + fl][ks + fh * 8];
#pragma unroll
            for (int nf = 0; nf < 5; ++nf) {
                bf16x8 b = *(const bf16x8*)&Ws[nf * 16 + fl][ks + fh * 8];
                acc[nf] = __builtin_amdgcn_mfma_f32_16x16x32_bf16(a, b, acc[nf], 0, 0, 0);
            }
        }
    }
#pragma unroll
    for (int nf = 0; nf < 5; ++nf) {
        const int c = nf * 16 + fl;
        const float bb = bo[c];
#pragma unroll
        for (int j = 0; j < 4; ++j) {
            const int r = row0 + wave * 16 + fh * 4 + j;
            const float y = tanhf(acc[nf][j] + bb);
            outy[(size_t)idx[r] * DOUT_ + c] = y;
        }
    }
}

extern "C" void kernel_launch(void* const* d_in, const int* in_sizes, int n_in,
                              void* d_out, int out_size, void* d_ws, size_t ws_size,
                              hipStream_t stream) {
    const float* encoded = (const float*)d_in[0];
    const float* hidden  = (const float*)d_in[1];
    const int*   idx     = (const int*)d_in[2];
    const float* w_ih    = (const float*)d_in[3];
    const float* w_hh    = (const float*)d_in[4];
    const float* b_ih    = (const float*)d_in[5];
    const float* b_hh    = (const float*)d_in[6];
    const float* w_out   = (const float*)d_in[7];
    const float* b_out   = (const float*)d_in[8];

    float* outy = (float*)d_out;
    float* outh = outy + (size_t)B_ * DOUT_;

    ushort_t* ws    = (ushort_t*)d_ws;
    ushort_t* wihb  = ws;
    ushort_t* whhb  = wihb + (size_t)L_ * G3_ * H_;
    ushort_t* woutb = whhb + (size_t)L_ * G3_ * H_;
    ushort_t* xb0   = woutb + (size_t)DOUT_ * H_;
    ushort_t* xb1   = xb0 + (size_t)NACT_ * H_;
    ushort_t* hb    = xb1 + (size_t)NACT_ * H_;
    uchar_t*  mask  = (uchar_t*)(hb + (size_t)L_ * NACT_ * H_);

    hipMemsetAsync(outy, 0, (size_t)B_ * DOUT_ * sizeof(float), stream);
    hipMemsetAsync(mask, 0, B_, stream);
    prep_all<<<2048, 256, 0, stream>>>(encoded, hidden, idx, w_ih, w_hh, w_out,
                                       wihb, whhb, woutb, xb0, hb, mask);

    ushort_t* xin = xb0;
    ushort_t* xout = xb1;
    for (int i = 0; i < L_; ++i) {
        gru_layer<<<1024, 256, 0, stream>>>(
            xin, hb + (size_t)i * NACT_ * H_, hidden + (size_t)i * B_ * H_,
            wihb + (size_t)i * G3_ * H_, whhb + (size_t)i * G3_ * H_,
            b_ih + (size_t)i * G3_, b_hh + (size_t)i * G3_, idx,
            outh + (size_t)i * B_ * H_, xout);
        ushort_t* t = xin; xin = xout; xout = t;
    }
    tail_kernel<<<2048, 256, 0, stream>>>(xin, woutb, b_out, idx, outy,
                                          hidden, mask, outh);
}

// Round 12
// 263.974 us; speedup vs baseline: 1.0984x; 1.0984x over previous
//
#include <hip/hip_runtime.h>

typedef unsigned short ushort_t;
typedef unsigned char uchar_t;
typedef unsigned int uint_t;
typedef __attribute__((ext_vector_type(8))) short bf16x8;
typedef __attribute__((ext_vector_type(4))) float f32x4;

constexpr int L_   = 3;
constexpr int B_   = 8192;
constexpr int H_   = 1024;
constexpr int DOUT_= 80;
constexpr int NACT_= 4096;
constexpr int G3_  = 3 * H_;

static __device__ __forceinline__ ushort_t f2bf(float f) {
    uint_t u = __float_as_uint(f);
    uint_t r = (u + 0x7FFFu + ((u >> 16) & 1u)) >> 16;
    return (ushort_t)r;
}

static __device__ __forceinline__ void gll16(const void* g, void* l) {
    __builtin_amdgcn_global_load_lds(
        (const __attribute__((address_space(1))) uint32_t*)g,
        (__attribute__((address_space(3))) uint32_t*)l, 16, 0, 0);
}

// ---------------- fused prep: mask + weight convert + gather/convert ----------------
__global__ void prep_all(const float* __restrict__ encoded, const float* __restrict__ hidden,
                         const int* __restrict__ idx,
                         const float* __restrict__ wih, const float* __restrict__ whh,
                         const float* __restrict__ wout,
                         ushort_t* __restrict__ oih, ushort_t* __restrict__ ohh,
                         ushort_t* __restrict__ oout,
                         ushort_t* __restrict__ x0, ushort_t* __restrict__ hb,
                         uchar_t* __restrict__ mask) {
    int tid = blockIdx.x * blockDim.x + threadIdx.x;
    int nth = gridDim.x * blockDim.x;
    if (tid < NACT_) mask[idx[tid]] = 1;
    const int NW = L_ * G3_ * H_ / 4;
    for (int i = tid; i < NW; i += nth) {
        float4 a = ((const float4*)wih)[i];
        ushort4 o; o.x = f2bf(a.x); o.y = f2bf(a.y); o.z = f2bf(a.z); o.w = f2bf(a.w);
        ((ushort4*)oih)[i] = o;
        float4 b = ((const float4*)whh)[i];
        ushort4 p; p.x = f2bf(b.x); p.y = f2bf(b.y); p.z = f2bf(b.z); p.w = f2bf(b.w);
        ((ushort4*)ohh)[i] = p;
    }
    const int NO = DOUT_ * H_ / 4;
    for (int i = tid; i < NO; i += nth) {
        float4 a = ((const float4*)wout)[i];
        ushort4 o; o.x = f2bf(a.x); o.y = f2bf(a.y); o.z = f2bf(a.z); o.w = f2bf(a.w);
        ((ushort4*)oout)[i] = o;
    }
    const int C4 = H_ / 4;
    const int PER = NACT_ * C4;
    for (int i = tid; i < 4 * PER; i += nth) {
        int seg = i / PER;
        int rem = i - seg * PER;
        int r = rem / C4, c = rem % C4;
        int gr = idx[r];
        const float* src = (seg == 0) ? (encoded + (size_t)gr * H_)
                                      : (hidden + ((size_t)(seg - 1) * B_ + gr) * H_);
        float4 v = ((const float4*)src)[c];
        ushort4 o; o.x = f2bf(v.x); o.y = f2bf(v.y); o.z = f2bf(v.z); o.w = f2bf(v.w);
        ushort_t* dst = (seg == 0) ? x0 : (hb + (size_t)(seg - 1) * NACT_ * H_);
        ((ushort4*)(dst + (size_t)r * H_))[c] = o;
    }
}

// ---------------- inactive-row copy, all 3 layers (rows disjoint from gru writes) ----------------
__global__ void copy_inactive(const float* __restrict__ hidden, const uchar_t* __restrict__ mask,
                              float* __restrict__ outh) {
    const int total = L_ * B_ * (H_ / 4);
    int i = blockIdx.x * blockDim.x + threadIdx.x;
    int nth = gridDim.x * blockDim.x;
    for (; i < total; i += nth) {
        int row = (i >> 8) & (B_ - 1);          // 256 float4 per row
        if (mask[row]) continue;
        ((float4*)outh)[i] = ((const float4*)hidden)[i];
    }
}

// ---------------- fused GRU layer: proven m97-structure, 512 threads (round-10 winner) ----------------
// 128-row x 64-col x 3-gate tile, 2-barrier K-loop, XOR swizzle (0 conflicts).
// 8 waves in a 2M x 4N grid (16-col wave tiles) -> 16 waves/CU for latency hiding.
__global__ __launch_bounds__(512, 4) void gru_layer(
    const ushort_t* __restrict__ xb,    // [N,H] bf16 layer input
    const ushort_t* __restrict__ hb,    // [N,H] bf16 gathered hidden
    const float* __restrict__ hid_full, // [B,H] fp32 hidden[i]
    const ushort_t* __restrict__ wih,   // [3H,H] bf16
    const ushort_t* __restrict__ whh,   // [3H,H] bf16
    const float* __restrict__ bih, const float* __restrict__ bhh,
    const int* __restrict__ idx,
    float* __restrict__ out_hid,        // [B,H] fp32
    ushort_t* __restrict__ xnext)       // [N,H] bf16
{
    __shared__ ushort_t As[128 * 64];   // 16 KB, row stride 64 bf16 (128 B)
    __shared__ ushort_t Ws[192 * 64];   // 24 KB, 3 gates x 64 rows

    const int tid = threadIdx.x;
    const int bid = blockIdx.x;
    const int swz = (bid & 7) * 64 + (bid >> 3);   // XCD-chunked, bijective (512 % 8 == 0)
    const int bn = swz & 15, bm = swz >> 4;
    const int row0 = bm * 128, col0 = bn * 64;
    const int wave = tid >> 6, lane = tid & 63;
    const int wr = wave >> 2, wc = wave & 3;       // 2M x 4N wave grid
    const int fl = lane & 15, fh = lane >> 4;
    const int srow = lane >> 3;                    // DMA: row-within-8 for this lane
    const int sxor = ((lane & 7) ^ srow) * 8;      // inverse-swizzled source 16B slot

    f32x4 accR[4] = {};
    f32x4 accZ[4] = {};
    f32x4 accN[2][4] = {};

#pragma unroll
    for (int ph = 0; ph < 2; ++ph) {
        const ushort_t* Asrc = ph ? hb : xb;
        const ushort_t* Wsrc = ph ? whh : wih;
        const ushort_t* abase[2];
        const ushort_t* wbase[3];
#pragma unroll
        for (int t = 0; t < 2; ++t)
            abase[t] = Asrc + (size_t)(row0 + wave * 16 + t * 8 + srow) * H_ + sxor;
#pragma unroll
        for (int t = 0; t < 3; ++t) {
            const int slot = wave * 24 + t * 8 + srow;   // flat W row 0..191 = gate*64 + col
            const int gate = slot >> 6, rowW = slot & 63;
            wbase[t] = Wsrc + (size_t)(gate * H_ + col0 + rowW) * H_ + sxor;
        }
        for (int kk = 0; kk < H_; kk += 64) {
            __syncthreads();
#pragma unroll
            for (int t = 0; t < 2; ++t)
                gll16(abase[t] + kk, &As[wave * 1024 + t * 512]);
#pragma unroll
            for (int t = 0; t < 3; ++t)
                gll16(wbase[t] + kk, &Ws[wave * 1536 + t * 512]);
            __syncthreads();
#pragma unroll
            for (int ks = 0; ks < 2; ++ks) {
                const int sl = ((ks * 4 + fh) ^ (fl & 7)) * 8;  // swizzled ds_read slot
                bf16x8 a[4];
#pragma unroll
                for (int m = 0; m < 4; ++m)
                    a[m] = *(const bf16x8*)&As[(wr * 64 + m * 16 + fl) * 64 + sl];
#pragma unroll
                for (int g = 0; g < 3; ++g) {
                    const bf16x8 b = *(const bf16x8*)&Ws[(g * 64 + wc * 16 + fl) * 64 + sl];
#pragma unroll
                    for (int m = 0; m < 4; ++m) {
                        if (g == 0)
                            accR[m] = __builtin_amdgcn_mfma_f32_16x16x32_bf16(a[m], b, accR[m], 0, 0, 0);
                        else if (g == 1)
                            accZ[m] = __builtin_amdgcn_mfma_f32_16x16x32_bf16(a[m], b, accZ[m], 0, 0, 0);
                        else
                            accN[ph][m] = __builtin_amdgcn_mfma_f32_16x16x32_bf16(a[m], b, accN[ph][m], 0, 0, 0);
                    }
                }
            }
        }
    }

    // epilogue: gate math, scatter into out_hid, write bf16 x for next layer
    {
        const int c = col0 + wc * 16 + fl;
        const float br_r = bih[c] + bhh[c];
        const float br_z = bih[H_ + c] + bhh[H_ + c];
        const float bi_n = bih[2 * H_ + c];
        const float bh_n = bhh[2 * H_ + c];
#pragma unroll
        for (int m = 0; m < 4; ++m) {
#pragma unroll
            for (int j = 0; j < 4; ++j) {
                const int r = row0 + wr * 64 + m * 16 + fh * 4 + j;
                const float vr = 1.f / (1.f + expf(-(accR[m][j] + br_r)));
                const float vz = 1.f / (1.f + expf(-(accZ[m][j] + br_z)));
                const float vn = tanhf(accN[0][m][j] + bi_n + vr * (accN[1][m][j] + bh_n));
                const int gr = idx[r];
                const float h0 = hid_full[(size_t)gr * H_ + c];
                const float ho = (1.f - vz) * vn + vz * h0;
                out_hid[(size_t)gr * H_ + c] = ho;
                xnext[(size_t)r * H_ + c] = f2bf(ho);
            }
        }
    }
}

// ---------------- head: y = tanh(x @ w_out^T + b_out), scatter ----------------
__global__ __launch_bounds__(256) void head_gemm(
    const ushort_t* __restrict__ xb, const ushort_t* __restrict__ wo,
    const float* __restrict__ bo, const int* __restrict__ idx,
    float* __restrict__ outy)
{
    __shared__ ushort_t Xs[64][72];
    __shared__ ushort_t Ws[80][72];
    const int tid = threadIdx.x;
    const int row0 = blockIdx.x * 64;
    const int lrow = tid >> 2, lseg = tid & 3;
    const int wave = tid >> 6, lane = tid & 63;
    const int fl = lane & 15, fh = lane >> 4;
    f32x4 acc[5] = {};

    for (int kk = 0; kk < H_; kk += 64) {
        __syncthreads();
        const ushort_t* xp = xb + (size_t)(row0 + lrow) * H_ + kk + lseg * 16;
        *(uint4*)&Xs[lrow][lseg * 16]     = *(const uint4*)xp;
        *(uint4*)&Xs[lrow][lseg * 16 + 8] = *(const uint4*)(xp + 8);
        for (int t = tid; t < 320; t += 256) {
            int r = t >> 2, s = t & 3;
            const ushort_t* wp = wo + (size_t)r * H_ + kk + s * 16;
            *(uint4*)&Ws[r][s * 16]     = *(const uint4*)wp;
            *(uint4*)&Ws[r][s * 16 + 8] = *(const uint4*)(wp + 8);
        }
        __syncthreads();
#pragma unroll
        for (int ks = 0; ks < 64; ks += 32) {
            bf16x8 a = *(const bf16x8*)&Xs[wave * 16 + fl][ks + fh * 8];
#pragma unroll
            for (int nf = 0; nf < 5; ++nf) {
                bf16x8 b = *(const bf16x8*)&Ws[nf * 16 + fl][ks + fh * 8];
                acc[nf] = __builtin_amdgcn_mfma_f32_16x16x32_bf16(a, b, acc[nf], 0, 0, 0);
            }
        }
    }
#pragma unroll
    for (int nf = 0; nf < 5; ++nf) {
        const int c = nf * 16 + fl;
        const float bb = bo[c];
#pragma unroll
        for (int j = 0; j < 4; ++j) {
            const int r = row0 + wave * 16 + fh * 4 + j;
            const float y = tanhf(acc[nf][j] + bb);
            outy[(size_t)idx[r] * DOUT_ + c] = y;
        }
    }
}

extern "C" void kernel_launch(void* const* d_in, const int* in_sizes, int n_in,
                              void* d_out, int out_size, void* d_ws, size_t ws_size,
                              hipStream_t stream) {
    const float* encoded = (const float*)d_in[0];
    const float* hidden  = (const float*)d_in[1];
    const int*   idx     = (const int*)d_in[2];
    const float* w_ih    = (const float*)d_in[3];
    const float* w_hh    = (const float*)d_in[4];
    const float* b_ih    = (const float*)d_in[5];
    const float* b_hh    = (const float*)d_in[6];
    const float* w_out   = (const float*)d_in[7];
    const float* b_out   = (const float*)d_in[8];

    float* outy = (float*)d_out;
    float* outh = outy + (size_t)B_ * DOUT_;

    ushort_t* ws    = (ushort_t*)d_ws;
    ushort_t* wihb  = ws;
    ushort_t* whhb  = wihb + (size_t)L_ * G3_ * H_;
    ushort_t* woutb = whhb + (size_t)L_ * G3_ * H_;
    ushort_t* xb0   = woutb + (size_t)DOUT_ * H_;
    ushort_t* xb1   = xb0 + (size_t)NACT_ * H_;
    ushort_t* hb    = xb1 + (size_t)NACT_ * H_;
    uchar_t*  mask  = (uchar_t*)(hb + (size_t)L_ * NACT_ * H_);

    hipMemsetAsync(outy, 0, (size_t)B_ * DOUT_ * sizeof(float), stream);
    hipMemsetAsync(mask, 0, B_, stream);
    prep_all<<<2048, 256, 0, stream>>>(encoded, hidden, idx, w_ih, w_hh, w_out,
                                       wihb, whhb, woutb, xb0, hb, mask);
    copy_inactive<<<2048, 256, 0, stream>>>(hidden, mask, outh);

    ushort_t* xin = xb0;
    ushort_t* xout = xb1;
    for (int i = 0; i < L_; ++i) {
        gru_layer<<<512, 512, 0, stream>>>(
            xin, hb + (size_t)i * NACT_ * H_, hidden + (size_t)i * B_ * H_,
            wihb + (size_t)i * G3_ * H_, whhb + (size_t)i * G3_ * H_,
            b_ih + (size_t)i * G3_, b_hh + (size_t)i * G3_, idx,
            outh + (size_t)i * B_ * H_, xout);
        ushort_t* t = xin; xin = xout; xout = t;
    }
    head_gemm<<<64, 256, 0, stream>>>(xin, woutb, b_out, idx, outy);
}